// Round 13
// baseline (220.035 us; speedup 1.0000x reference)
//
#include <hip/hip_runtime.h>

#define TT 200
#define BB 256
#define DD 128
#define HH 128
#define NG 896  // 7*H, semantic col = g*128 + u
#define CH 16   // xg chunk (timesteps) double-buffered in LDS

typedef _Float16 half8 __attribute__((ext_vector_type(8)));
typedef float float4v __attribute__((ext_vector_type(4)));
typedef int int4v __attribute__((ext_vector_type(4)));

__device__ __forceinline__ float rcpf_(float x) { return __builtin_amdgcn_rcpf(x); }
__device__ __forceinline__ float sigmoidf_(float x) { return rcpf_(1.f + __expf(-x)); }
__device__ __forceinline__ float tanhf_(float x) { return 1.f - 2.f * rcpf_(__expf(2.f * x) + 1.f); }
__device__ __forceinline__ float softplusf_(float x) {
  return fmaxf(x, 0.f) + 0.69314718056f * __log2f(1.f + __expf(-fabsf(x)));
}

// W_x transpose + f16 cast: WxT[col][k], col semantic (g*128+u)
__global__ __launch_bounds__(256) void wtrans_k(const float* __restrict__ Wx,
    _Float16* __restrict__ WxT) {
  int idx = blockIdx.x * 256 + threadIdx.x;
  if (idx < DD * NG) {
    int k = idx / NG, col = idx % NG;
    WxT[col * DD + k] = (_Float16)Wx[idx];
  }
}

// W_h i8 quantization, per-column scale (r12, validated)
__global__ __launch_bounds__(256) void wquant_k(const float* __restrict__ Wh,
    char* __restrict__ WhQ, float* __restrict__ wscale) {
  int col = blockIdx.x * 256 + threadIdx.x;
  if (col >= NG) return;
  float m = 0.f;
  for (int k = 0; k < DD; ++k) m = fmaxf(m, fabsf(Wh[k * NG + col]));
  float mm = m > 0.f ? m : 1.f;
  float inv = 127.f * rcpf_(mm);
  for (int k = 0; k < DD; ++k)
    WhQ[col * DD + k] = (char)__float2int_rn(Wh[k * NG + col] * inv);
  wscale[col] = mm * (1.f / 127.f);
}

// Fused producer/consumer CT-LSTM. 1 block/sample, 768 threads = 12 waves.
// Waves 0-7 (rec): r12's i8-MFMA recurrence, 1 __syncthreads per step.
// Waves 8-11 (gemm): while rec runs chunk c, compute chunk c+1's xg
// (x[b,t,:]@W_x + bias, f16 MFMA) into the other LDS buffer — one 16-col tile
// per barrier slot (slots 2..15). Barrier cadence gives producer→consumer
// visibility for free; no global xg traffic, no extra dispatches.
__global__ __launch_bounds__(768) void fused_k(const float* __restrict__ x,
    const float* __restrict__ dur, const int* __restrict__ rep,
    const _Float16* __restrict__ WxT, const char* __restrict__ WhQ,
    const float* __restrict__ wscale, const float* __restrict__ bias,
    float* __restrict__ out) {
  int b = blockIdx.x, j = threadIdx.x;
  int tend = rep[b];
  __shared__ __align__(16) _Float16 xgL[2][CH][1024];  // [buf][t%CH][u*8+g], 64KB
  __shared__ __align__(16) char hq[2][HH];
  __shared__ float dlds[TT];
  int waveId = j >> 6, l = j & 63, lr = l & 15, lg = l >> 4;
  bool isRec = waveId < 8;
  int u = (waveId & 7) * 16 + lr;

  for (int i = j; i < TT; i += 768) dlds[i] = dur[b * TT + i];

  // ---- rec-wave state ----
  int4v wbq[7][2];
  float sg[7];
  float c_s = 0.f, cb_s = 0.f;
  if (isRec) {
#pragma unroll
    for (int g = 0; g < 7; ++g) {
#pragma unroll
      for (int m = 0; m < 2; ++m)
        wbq[g][m] = *(const int4v*)(WhQ + (size_t)(g * HH + u) * DD + m * 64 + lg * 16);
      sg[g] = wscale[g * HH + u] * (1.f / 127.f);
    }
    if (lg == 0) { hq[0][u] = (char)0; hq[1][u] = (char)0; }
  }

  // ---- gemm-wave state + prologue (chunk 0) ----
  int gw = waveId - 8;  // 0..3
  half8 Acur[4];
  float4v Anraw[8];

#define GLOAD_A(TROW0)                                                           \
  do {                                                                           \
    int t_r = min((TROW0) + lr, TT - 1);                                         \
    const float* xp = x + ((size_t)b * TT + t_r) * DD + lg * 8;                  \
    _Pragma("unroll") for (int kk = 0; kk < 4; ++kk) {                           \
      Anraw[2 * kk] = *(const float4v*)(xp + kk * 32);                           \
      Anraw[2 * kk + 1] = *(const float4v*)(xp + kk * 32 + 4);                   \
    }                                                                            \
  } while (0)

#define CVT_A()                                                                  \
  do {                                                                           \
    _Pragma("unroll") for (int kk = 0; kk < 4; ++kk) {                           \
      half8 a;                                                                   \
      a[0] = (_Float16)Anraw[2 * kk][0]; a[1] = (_Float16)Anraw[2 * kk][1];      \
      a[2] = (_Float16)Anraw[2 * kk][2]; a[3] = (_Float16)Anraw[2 * kk][3];      \
      a[4] = (_Float16)Anraw[2 * kk + 1][0]; a[5] = (_Float16)Anraw[2 * kk + 1][1]; \
      a[6] = (_Float16)Anraw[2 * kk + 1][2]; a[7] = (_Float16)Anraw[2 * kk + 1][3]; \
      Acur[kk] = a;                                                              \
    }                                                                            \
  } while (0)

#define SLICE(CT, WBUF)                                                          \
  do {                                                                           \
    int col = (CT) * 16 + lr;                                                    \
    half8 bf[4];                                                                 \
    _Pragma("unroll") for (int kk = 0; kk < 4; ++kk)                             \
        bf[kk] = *(const half8*)(WxT + (size_t)col * DD + kk * 32 + lg * 8);     \
    float bv = bias[col];                                                        \
    float4v acc = (float4v){bv, bv, bv, bv};                                     \
    _Pragma("unroll") for (int kk = 0; kk < 4; ++kk)                             \
        acc = __builtin_amdgcn_mfma_f32_16x16x32_f16(Acur[kk], bf[kk], acc, 0, 0, 0); \
    int u8g = ((col & 127) << 3) | (col >> 7);                                   \
    _Pragma("unroll") for (int r = 0; r < 4; ++r)                                \
        xgL[WBUF][lg * 4 + r][u8g] = (_Float16)acc[r];                           \
  } while (0)

  if (!isRec) {
    GLOAD_A(0);
    CVT_A();
#pragma unroll
    for (int s2 = 0; s2 < 14; ++s2) SLICE(gw * 14 + s2, 0);
    if (CH <= tend) GLOAD_A(CH);
    CVT_A();  // Acur = A(chunk 1) (stale-unused if no chunk 1)
  }
  __syncthreads();  // chunk 0 ready, hq init visible

  // ---- main loop ----
#define STEP(T, S, PIN, POUT)                                                    \
  do {                                                                           \
    float dt = dlds[T];                                                          \
    half8 xv = *(const half8*)(prd + (S) * 1024 + u * 8);                        \
    int4v aq0 = *(const int4v*)&hq[PIN][lg * 16];                                \
    int4v aq1 = *(const int4v*)&hq[PIN][64 + lg * 16];                           \
    int4v acc[7];                                                                \
    _Pragma("unroll") for (int g = 0; g < 7; ++g) acc[g] = (int4v){0, 0, 0, 0};  \
    _Pragma("unroll") for (int g = 0; g < 7; ++g)                                \
        acc[g] = __builtin_amdgcn_mfma_i32_16x16x64_i8(aq0, wbq[g][0], acc[g], 0, 0, 0); \
    _Pragma("unroll") for (int g = 0; g < 7; ++g)                                \
        acc[g] = __builtin_amdgcn_mfma_i32_16x16x64_i8(aq1, wbq[g][1], acc[g], 0, 0, 0); \
    float gv[7];                                                                 \
    _Pragma("unroll") for (int g = 0; g < 7; ++g)                                \
        gv[g] = (float)acc[g][0] * sg[g] + (float)xv[g];                         \
    float iv = sigmoidf_(gv[0]), fv = sigmoidf_(gv[1]);                          \
    float zv = tanhf_(gv[2]), ov = sigmoidf_(gv[3]);                             \
    float ibv = sigmoidf_(gv[4]), fbv = sigmoidf_(gv[5]);                        \
    float dv = softplusf_(gv[6]);                                                \
    float cc = fv * c_s + iv * zv;                                               \
    cb_s = fbv * cb_s + ibv * zv;                                                \
    float cn = cb_s + (cc - cb_s) * __expf(-dv * dt);                            \
    float hn = ov * tanhf_(cn);                                                  \
    c_s = cn;                                                                    \
    char hb = (char)__float2int_rn(hn * 127.f);                                  \
    if (lg == 0) {                                                               \
      if ((T) == tend) {                                                         \
        out[b * HH + u] = hn;                                                    \
        out[BB * HH + b * HH + u] = cn;                                          \
      }                                                                          \
      hq[POUT][u] = hb;                                                          \
    }                                                                            \
  } while (0)

  int nchunk = tend / CH + 1;
  for (int c = 0; c < nchunk; ++c) {
    int base = c * CH;
    int smax = min(CH - 1, tend - base);
    bool doNext = (base + CH) <= tend;          // chunk c+1 exists
    bool doNext2 = (base + 2 * CH) <= tend;     // chunk c+2 exists
    const _Float16* prd = &xgL[c & 1][0][0];
    int wbuf = (c + 1) & 1;
#pragma unroll
    for (int s = 0; s < CH; ++s) {
      if (s <= smax) {  // block-uniform
        int t = base + s;
        if (isRec) {
          if ((s & 1) == 0) STEP(t, s, 0, 1);
          else              STEP(t, s, 1, 0);
        } else {
          if (s == 0) {
            if (doNext2) GLOAD_A(base + 2 * CH);  // A(c+2), used next chunk
          } else if (s >= 2) {
            if (doNext) SLICE(gw * 14 + (s - 2), wbuf);
          }
          if (s == CH - 1 && doNext2) CVT_A();    // Acur = A(c+2)
        }
        __syncthreads();
      }
    }
  }
#undef STEP
#undef SLICE
#undef CVT_A
#undef GLOAD_A
}

extern "C" void kernel_launch(void* const* d_in, const int* in_sizes, int n_in,
                              void* d_out, int out_size, void* d_ws, size_t ws_size,
                              hipStream_t stream) {
  const float* x = (const float*)d_in[0];
  const float* dur = (const float*)d_in[1];
  const int* rep = (const int*)d_in[2];
  const float* Wx = (const float*)d_in[3];
  const float* Wh = (const float*)d_in[4];
  const float* bias = (const float*)d_in[5];
  float* out = (float*)d_out;
  char* ws = (char*)d_ws;

  size_t off = 0;
  _Float16* WxT = (_Float16*)(ws + off); off += (size_t)NG * DD * 2;
  char* WhQ = (char*)(ws + off); off += (size_t)NG * DD;
  off = (off + 255) & ~(size_t)255;
  float* wscale = (float*)(ws + off); off += (size_t)NG * 4;

  hipLaunchKernelGGL(wtrans_k, dim3((DD * NG + 255) / 256), dim3(256), 0, stream,
                     Wx, WxT);
  hipLaunchKernelGGL(wquant_k, dim3((NG + 255) / 256), dim3(256), 0, stream,
                     Wh, WhQ, wscale);
  hipLaunchKernelGGL(fused_k, dim3(BB), dim3(768), 0, stream,
                     x, dur, rep, WxT, WhQ, wscale, bias, out);
}

// Round 14
// 190.477 us; speedup vs baseline: 1.1552x; 1.1552x over previous
//
#include <hip/hip_runtime.h>

#define TT 200
#define BB 256
#define DD 128
#define HH 128
#define NG 896    // 7*H semantic gate dim (gate-major: col = g*128 + u)
#define NGP 1024  // padded xg: pcol = u*8 + gate, gate 7 = zero pad

typedef _Float16 half8 __attribute__((ext_vector_type(8)));
typedef _Float16 half4 __attribute__((ext_vector_type(4)));
typedef float float4v __attribute__((ext_vector_type(4)));
typedef int int4v __attribute__((ext_vector_type(4)));

__device__ __forceinline__ float rcpf_(float x) { return __builtin_amdgcn_rcpf(x); }
__device__ __forceinline__ float sigmoidf_(float x) { return rcpf_(1.f + __expf(-x)); }
__device__ __forceinline__ float tanhf_(float x) { return 1.f - 2.f * rcpf_(__expf(2.f * x) + 1.f); }
// softplus(x) = max(x,0) + ln(1+exp(-|x|))
__device__ __forceinline__ float softplusf_(float x) {
  return fmaxf(x, 0.f) + 0.69314718056f * __log2f(1.f + __expf(-fabsf(x)));
}

// Weight prep for xg path: WxTp[pcol][k] (pcol=u*8+g, padded), bias_p[pcol]
__global__ __launch_bounds__(256) void wtrans_k(const float* __restrict__ Wx,
    const float* __restrict__ bias, _Float16* __restrict__ WxTp, float* __restrict__ bias_p) {
  int idx = blockIdx.x * 256 + threadIdx.x;
  if (idx < NGP * DD) {  // WxTp
    int pcol = idx >> 7, k = idx & 127;
    int u = pcol >> 3, g = pcol & 7;
    WxTp[idx] = (g < 7) ? (_Float16)Wx[k * NG + g * HH + u] : (_Float16)0.f;
  } else if (idx < NGP * DD + NGP) {  // bias_p
    int pcol = idx - NGP * DD;
    int u = pcol >> 3, g = pcol & 7;
    bias_p[pcol] = (g < 7) ? bias[g * HH + u] : 0.f;
  }
}

// W_h int8 quantization, per-column scale (r12, validated)
__global__ __launch_bounds__(256) void wquant_k(const float* __restrict__ Wh,
    char* __restrict__ WhQ, float* __restrict__ wscale) {
  int col = blockIdx.x * 256 + threadIdx.x;
  if (col >= NG) return;
  float m = 0.f;
  for (int k = 0; k < DD; ++k) m = fmaxf(m, fabsf(Wh[k * NG + col]));
  float mm = m > 0.f ? m : 1.f;
  float inv = 127.f * rcpf_(mm);
  for (int k = 0; k < DD; ++k)
    WhQ[col * DD + k] = (char)__float2int_rn(Wh[k * NG + col] * inv);
  wscale[col] = mm * (1.f / 127.f);
}

// xg GEMM with COALESCED writes: C-tile staged through Ald (free after the
// A-fragments move to registers), then half8 stores (16 lanes x 16 B = 256 B).
// r12's version stored 64 scalar f16 per lane (32-B transactions, ~2.2 TB/s).
__global__ __launch_bounds__(256, 2) void xg_gemm_k(const float* __restrict__ x,
    const _Float16* __restrict__ WxTp, const float* __restrict__ bias_p,
    _Float16* __restrict__ xg, int t0) {
  int mt = blockIdx.x;
  __shared__ _Float16 Ald[128][136];
  __shared__ _Float16 Bld[128][136];
  int tid = threadIdx.x;
  int G0 = mt * 128;
  int t = t0 + (G0 >> 8);
  int b0 = G0 & 255;
  {
    int r = tid >> 5, kq = (tid & 31) << 2;
#pragma unroll
    for (int it = 0; it < 16; ++it) {
      int row = r + it * 8;
      float4v xv = *(const float4v*)(x + ((size_t)(b0 + row) * TT + t) * DD + kq);
      half4 h4 = {(_Float16)xv[0], (_Float16)xv[1], (_Float16)xv[2], (_Float16)xv[3]};
      *(half4*)&Ald[row][kq] = h4;
    }
  }
  __syncthreads();
  int wv = tid >> 6, l = tid & 63, lr = l & 15, lk8 = (l >> 4) << 3;
  half8 af[2][4];
#pragma unroll
  for (int mf = 0; mf < 2; ++mf)
#pragma unroll
    for (int kk = 0; kk < 4; ++kk)
      af[mf][kk] = *(const half8*)&Ald[wv * 32 + mf * 16 + lr][kk * 32 + lk8];
  int r4 = (l >> 4) << 2;

  for (int nt = 0; nt < 8; ++nt) {
    for (int i = tid; i < 128 * 16; i += 256) {
      int r = i >> 4, c8 = (i & 15) << 3;
      *(half8*)&Bld[r][c8] = *(const half8*)(WxTp + (size_t)(nt * 128 + r) * DD + c8);
    }
    __syncthreads();  // Bld ready; prev iter's Ald reads complete
    float4v acc[2][8];
#pragma unroll
    for (int a = 0; a < 2; ++a)
#pragma unroll
      for (int q = 0; q < 8; ++q) acc[a][q] = (float4v){0.f, 0.f, 0.f, 0.f};
#pragma unroll
    for (int kk = 0; kk < 4; ++kk) {
#pragma unroll
      for (int nf = 0; nf < 8; ++nf) {
        half8 bv = *(const half8*)&Bld[nf * 16 + lr][kk * 32 + lk8];
        acc[0][nf] = __builtin_amdgcn_mfma_f32_16x16x32_f16(af[0][kk], bv, acc[0][nf], 0, 0, 0);
        acc[1][nf] = __builtin_amdgcn_mfma_f32_16x16x32_f16(af[1][kk], bv, acc[1][nf], 0, 0, 0);
      }
    }
    // stage C (+bias) into Ald
#pragma unroll
    for (int nf = 0; nf < 8; ++nf) {
      int colL = nf * 16 + lr;
      float bv = bias_p[nt * 128 + colL];
#pragma unroll
      for (int mf = 0; mf < 2; ++mf) {
        int rowL = wv * 32 + mf * 16 + r4;
#pragma unroll
        for (int rr = 0; rr < 4; ++rr)
          Ald[rowL + rr][colL] = (_Float16)(acc[mf][nf][rr] + bv);
      }
    }
    __syncthreads();  // staging visible; Bld reads drained
    // coalesced global write: 128 rows x 16 half8 col-groups
#pragma unroll
    for (int it = 0; it < 8; ++it) {
      int slot = tid + it * 256;
      int row = slot >> 4, cg = slot & 15;
      half8 v = *(const half8*)&Ald[row][cg * 8];
      *(half8*)&xg[(size_t)(G0 + row) * NGP + nt * 128 + cg * 8] = v;
    }
  }
}

// MFMA recurrence, i8 (r12 champion) + wave-stagger: waves 4-7 sleep ~256 cy at
// step start so their MFMA cluster runs under waves 0-3's VALU phase (waves w
// and w+4 share a SIMD). Pure timing change — no correctness impact.
__global__ __launch_bounds__(512, 2) void rec_k(const _Float16* __restrict__ xg,
    const float* __restrict__ dur, const int* __restrict__ rep,
    const char* __restrict__ WhQ, const float* __restrict__ wscale,
    float* __restrict__ out,
    char* __restrict__ st_h, float* __restrict__ st_c, float* __restrict__ st_cb,
    int t0, int t1) {
  int b = blockIdx.x, j = threadIdx.x;
  int tend = rep[b];
  if (t0 > tend) return;  // block-uniform
  int tstop = min(t1 - 1, tend);
  __shared__ __align__(16) char hq[2][HH];  // i8 h, double-buffered
  __shared__ float dlds[TT];
  int w = j >> 6, l = j & 63, lr = l & 15, lg = l >> 4;
  int u = w * 16 + lr;
  bool lateWave = (w >= 4);

  // B-fragments: wbq[g][m] = WhQ[col=g*128+u][k = m*64 + lg*16 .. +16] (16 i8)
  int4v wbq[7][2];
#pragma unroll
  for (int g = 0; g < 7; ++g)
#pragma unroll
    for (int m = 0; m < 2; ++m)
      wbq[g][m] = *(const int4v*)(WhQ + (size_t)(g * HH + u) * DD + m * 64 + lg * 16);
  float sg[7];
#pragma unroll
  for (int g = 0; g < 7; ++g) sg[g] = wscale[g * HH + u] * (1.f / 127.f);
  for (int i = j; i < TT; i += 512) dlds[i] = dur[b * TT + i];
  float c_s = 0.f, cb_s = 0.f;
  if (lg == 0) {
    hq[0][u] = (t0 == 0) ? (char)0 : st_h[b * HH + u];
    hq[1][u] = (char)0;
  }
  if (t0 != 0) {
    c_s = st_c[b * HH + u];
    cb_s = st_cb[b * HH + u];
  }
  __syncthreads();

  const _Float16* xgp = xg + (size_t)b * NGP + u * 8;  // + step*stp, aligned 16B
  const size_t stp = (size_t)BB * NGP;
  half8 cur[8], nxt[8];
#pragma unroll
  for (int i = 0; i < 8; ++i)
    cur[i] = *(const half8*)(xgp + (size_t)(min(t0 + i, tstop) - t0) * stp);
  char hqsave = 0;

#define STEP(T, CUR, PIN, POUT)                                                  \
  do {                                                                           \
    if (lateWave) asm volatile("s_sleep 4");                                     \
    float dt = dlds[T];                                                          \
    int4v aq0 = *(const int4v*)&hq[PIN][lg * 16];                                \
    int4v aq1 = *(const int4v*)&hq[PIN][64 + lg * 16];                           \
    int4v acc[7];                                                                \
    _Pragma("unroll") for (int g = 0; g < 7; ++g) acc[g] = (int4v){0, 0, 0, 0};  \
    _Pragma("unroll") for (int g = 0; g < 7; ++g)                                \
        acc[g] = __builtin_amdgcn_mfma_i32_16x16x64_i8(aq0, wbq[g][0], acc[g], 0, 0, 0); \
    _Pragma("unroll") for (int g = 0; g < 7; ++g)                                \
        acc[g] = __builtin_amdgcn_mfma_i32_16x16x64_i8(aq1, wbq[g][1], acc[g], 0, 0, 0); \
    float gv[7];                                                                 \
    _Pragma("unroll") for (int g = 0; g < 7; ++g)                                \
        gv[g] = (float)acc[g][0] * sg[g] + (float)CUR[g];                        \
    float iv = sigmoidf_(gv[0]), fv = sigmoidf_(gv[1]);                          \
    float zv = tanhf_(gv[2]), ov = sigmoidf_(gv[3]);                             \
    float ibv = sigmoidf_(gv[4]), fbv = sigmoidf_(gv[5]);                        \
    float dv = softplusf_(gv[6]);                                                \
    float cc = fv * c_s + iv * zv;                                               \
    cb_s = fbv * cb_s + ibv * zv;                                                \
    float cn = cb_s + (cc - cb_s) * __expf(-dv * dt);                            \
    float hn = ov * tanhf_(cn);                                                  \
    c_s = cn;                                                                    \
    char hb = (char)__float2int_rn(hn * 127.f);                                  \
    hqsave = hb;                                                                 \
    if (lg == 0) {                                                               \
      if ((T) == tend) {                                                         \
        out[b * HH + u] = hn;                                                    \
        out[BB * HH + b * HH + u] = cn;                                          \
      }                                                                          \
      hq[POUT][u] = hb;                                                          \
    }                                                                            \
    __syncthreads();                                                             \
  } while (0)

  for (int tb = t0; tb <= tstop; tb += 8) {
#pragma unroll
    for (int i = 0; i < 8; ++i)
      nxt[i] = *(const half8*)(xgp + (size_t)(min(tb + 8 + i, tstop) - t0) * stp);
    STEP(tb, cur[0], 0, 1);
    if (tb + 1 <= tstop) STEP(tb + 1, cur[1], 1, 0);
    if (tb + 2 <= tstop) STEP(tb + 2, cur[2], 0, 1);
    if (tb + 3 <= tstop) STEP(tb + 3, cur[3], 1, 0);
    if (tb + 4 <= tstop) STEP(tb + 4, cur[4], 0, 1);
    if (tb + 5 <= tstop) STEP(tb + 5, cur[5], 1, 0);
    if (tb + 6 <= tstop) STEP(tb + 6, cur[6], 0, 1);
    if (tb + 7 <= tstop) STEP(tb + 7, cur[7], 1, 0);
#pragma unroll
    for (int i = 0; i < 8; ++i) cur[i] = nxt[i];
  }
#undef STEP

  if (tstop < tend && lg == 0) {  // save state for next chunk
    st_h[b * HH + u] = hqsave;
    st_c[b * HH + u] = c_s;
    st_cb[b * HH + u] = cb_s;
  }
}

extern "C" void kernel_launch(void* const* d_in, const int* in_sizes, int n_in,
                              void* d_out, int out_size, void* d_ws, size_t ws_size,
                              hipStream_t stream) {
  const float* x = (const float*)d_in[0];
  const float* dur = (const float*)d_in[1];
  const int* rep = (const int*)d_in[2];
  const float* Wx = (const float*)d_in[3];
  const float* Wh = (const float*)d_in[4];
  const float* bias = (const float*)d_in[5];
  float* out = (float*)d_out;
  char* ws = (char*)d_ws;

  size_t off = 0;
  _Float16* WxTp = (_Float16*)(ws + off); off += (size_t)NGP * DD * 2;
  float* bias_p = (float*)(ws + off); off += (size_t)NGP * 4;
  char* WhQ = (char*)(ws + off); off += (size_t)NG * DD;
  float* wscale = (float*)(ws + off); off += (size_t)NG * 4;
  char* st_h = (char*)(ws + off); off += (size_t)BB * HH;
  float* st_c = (float*)(ws + off); off += (size_t)BB * HH * 4;
  float* st_cb = (float*)(ws + off); off += (size_t)BB * HH * 4;
  off = (off + 255) & ~(size_t)255;
  _Float16* xgbuf = (_Float16*)(ws + off);

  size_t avail = ws_size > off ? ws_size - off : 0;
  size_t perT = (size_t)BB * NGP * 2;
  int Tc = (int)(avail / perT);
  if (Tc > TT) Tc = TT;
  if (Tc < 1) Tc = 1;

  int nprep = NGP * DD + NGP;
  hipLaunchKernelGGL(wtrans_k, dim3((nprep + 255) / 256), dim3(256), 0, stream,
                     Wx, bias, WxTp, bias_p);
  hipLaunchKernelGGL(wquant_k, dim3((NG + 255) / 256), dim3(256), 0, stream,
                     Wh, WhQ, wscale);
  for (int t0 = 0; t0 < TT; t0 += Tc) {
    int t1 = t0 + Tc;
    if (t1 > TT) t1 = TT;
    int mtiles = (t1 - t0) * BB / 128;
    hipLaunchKernelGGL(xg_gemm_k, dim3(mtiles), dim3(256), 0, stream,
                       x, WxTp, bias_p, xgbuf, t0);
    hipLaunchKernelGGL(rec_k, dim3(BB), dim3(512), 0, stream,
                       xgbuf, dur, rep, WhQ, wscale, out, st_h, st_c, st_cb, t0, t1);
  }
}

// Round 15
// 158.058 us; speedup vs baseline: 1.3921x; 1.2051x over previous
//
#include <hip/hip_runtime.h>

#define TT 200
#define BB 256
#define DD 128
#define HH 128
#define NG 896    // 7*H semantic gate dim (gate-major: col = g*128 + u)
#define NGP 1024  // padded xg: pcol = u*8 + gate, gate 7 = zero pad

typedef _Float16 half8 __attribute__((ext_vector_type(8)));
typedef _Float16 half4 __attribute__((ext_vector_type(4)));
typedef float float4v __attribute__((ext_vector_type(4)));
typedef int int4v __attribute__((ext_vector_type(4)));

__device__ __forceinline__ float rcpf_(float x) { return __builtin_amdgcn_rcpf(x); }
__device__ __forceinline__ float sigmoidf_(float x) { return rcpf_(1.f + __expf(-x)); }
__device__ __forceinline__ float tanhf_(float x) { return 1.f - 2.f * rcpf_(__expf(2.f * x) + 1.f); }
// softplus(x) = max(x,0) + ln(1+exp(-|x|))
__device__ __forceinline__ float softplusf_(float x) {
  return fmaxf(x, 0.f) + 0.69314718056f * __log2f(1.f + __expf(-fabsf(x)));
}

// Weight prep for xg path: WxTp[pcol][k] (pcol=u*8+g, padded), bias_p[pcol]
__global__ __launch_bounds__(256) void wtrans_k(const float* __restrict__ Wx,
    const float* __restrict__ bias, _Float16* __restrict__ WxTp, float* __restrict__ bias_p) {
  int idx = blockIdx.x * 256 + threadIdx.x;
  if (idx < NGP * DD) {  // WxTp
    int pcol = idx >> 7, k = idx & 127;
    int u = pcol >> 3, g = pcol & 7;
    WxTp[idx] = (g < 7) ? (_Float16)Wx[k * NG + g * HH + u] : (_Float16)0.f;
  } else if (idx < NGP * DD + NGP) {  // bias_p
    int pcol = idx - NGP * DD;
    int u = pcol >> 3, g = pcol & 7;
    bias_p[pcol] = (g < 7) ? bias[g * HH + u] : 0.f;
  }
}

// W_h i8 quantization — PARALLEL version. 14 blocks x 256 threads, 64 cols per
// block. Thread (c=tid&63, kq=tid>>6) holds 32 values of column col0+c in
// registers (row reads coalesced across c), 4-way LDS max-combine, quantize
// from registers. Replaces the 4-block latency-chain version (~30 us -> ~2 us).
__global__ __launch_bounds__(256) void wquant_k(const float* __restrict__ Wh,
    char* __restrict__ WhQ, float* __restrict__ wscale) {
  __shared__ float redmax[4][64];
  int tid = threadIdx.x;
  int c = tid & 63, kq = tid >> 6;
  int col = blockIdx.x * 64 + c;
  float v[32];
  float m = 0.f;
#pragma unroll
  for (int i = 0; i < 32; ++i) {
    v[i] = Wh[(size_t)(kq * 32 + i) * NG + col];
    m = fmaxf(m, fabsf(v[i]));
  }
  redmax[kq][c] = m;
  __syncthreads();
  float mm = fmaxf(fmaxf(redmax[0][c], redmax[1][c]),
                   fmaxf(redmax[2][c], redmax[3][c]));
  mm = mm > 0.f ? mm : 1.f;
  float inv = 127.f * rcpf_(mm);
  char q[32];
#pragma unroll
  for (int i = 0; i < 32; ++i) q[i] = (char)__float2int_rn(v[i] * inv);
#pragma unroll
  for (int i = 0; i < 8; ++i)
    *(int*)&WhQ[(size_t)col * DD + kq * 32 + i * 4] = *(int*)&q[i * 4];
  if (kq == 0) wscale[col] = mm * (1.f / 127.f);
}

// xg GEMM with coalesced writes (r14): C staged through Ald, half8 stores.
__global__ __launch_bounds__(256, 2) void xg_gemm_k(const float* __restrict__ x,
    const _Float16* __restrict__ WxTp, const float* __restrict__ bias_p,
    _Float16* __restrict__ xg, int t0) {
  int mt = blockIdx.x;
  __shared__ _Float16 Ald[128][136];
  __shared__ _Float16 Bld[128][136];
  int tid = threadIdx.x;
  int G0 = mt * 128;
  int t = t0 + (G0 >> 8);
  int b0 = G0 & 255;
  {
    int r = tid >> 5, kq = (tid & 31) << 2;
#pragma unroll
    for (int it = 0; it < 16; ++it) {
      int row = r + it * 8;
      float4v xv = *(const float4v*)(x + ((size_t)(b0 + row) * TT + t) * DD + kq);
      half4 h4 = {(_Float16)xv[0], (_Float16)xv[1], (_Float16)xv[2], (_Float16)xv[3]};
      *(half4*)&Ald[row][kq] = h4;
    }
  }
  __syncthreads();
  int wv = tid >> 6, l = tid & 63, lr = l & 15, lk8 = (l >> 4) << 3;
  half8 af[2][4];
#pragma unroll
  for (int mf = 0; mf < 2; ++mf)
#pragma unroll
    for (int kk = 0; kk < 4; ++kk)
      af[mf][kk] = *(const half8*)&Ald[wv * 32 + mf * 16 + lr][kk * 32 + lk8];
  int r4 = (l >> 4) << 2;

  for (int nt = 0; nt < 8; ++nt) {
    for (int i = tid; i < 128 * 16; i += 256) {
      int r = i >> 4, c8 = (i & 15) << 3;
      *(half8*)&Bld[r][c8] = *(const half8*)(WxTp + (size_t)(nt * 128 + r) * DD + c8);
    }
    __syncthreads();  // Bld ready; prev iter's Ald reads complete
    float4v acc[2][8];
#pragma unroll
    for (int a = 0; a < 2; ++a)
#pragma unroll
      for (int q = 0; q < 8; ++q) acc[a][q] = (float4v){0.f, 0.f, 0.f, 0.f};
#pragma unroll
    for (int kk = 0; kk < 4; ++kk) {
#pragma unroll
      for (int nf = 0; nf < 8; ++nf) {
        half8 bv = *(const half8*)&Bld[nf * 16 + lr][kk * 32 + lk8];
        acc[0][nf] = __builtin_amdgcn_mfma_f32_16x16x32_f16(af[0][kk], bv, acc[0][nf], 0, 0, 0);
        acc[1][nf] = __builtin_amdgcn_mfma_f32_16x16x32_f16(af[1][kk], bv, acc[1][nf], 0, 0, 0);
      }
    }
    // stage C (+bias) into Ald
#pragma unroll
    for (int nf = 0; nf < 8; ++nf) {
      int colL = nf * 16 + lr;
      float bv = bias_p[nt * 128 + colL];
#pragma unroll
      for (int mf = 0; mf < 2; ++mf) {
        int rowL = wv * 32 + mf * 16 + r4;
#pragma unroll
        for (int rr = 0; rr < 4; ++rr)
          Ald[rowL + rr][colL] = (_Float16)(acc[mf][nf][rr] + bv);
      }
    }
    __syncthreads();  // staging visible; Bld reads drained
    // coalesced global write: 128 rows x 16 half8 col-groups
#pragma unroll
    for (int it = 0; it < 8; ++it) {
      int slot = tid + it * 256;
      int row = slot >> 4, cg = slot & 15;
      half8 v = *(const half8*)&Ald[row][cg * 8];
      *(half8*)&xg[(size_t)(G0 + row) * NGP + nt * 128 + cg * 8] = v;
    }
  }
}

// MFMA recurrence, i8 weights+h (r12 champion, no stagger): 1 block/sample,
// 512 threads, one __syncthreads per step, 8-batch xg register prefetch.
// h@W_h via mfma_i32_16x16x64_i8 (K=128 in 2 MFMAs/gate at 2x f16 rate).
__global__ __launch_bounds__(512, 2) void rec_k(const _Float16* __restrict__ xg,
    const float* __restrict__ dur, const int* __restrict__ rep,
    const char* __restrict__ WhQ, const float* __restrict__ wscale,
    float* __restrict__ out,
    char* __restrict__ st_h, float* __restrict__ st_c, float* __restrict__ st_cb,
    int t0, int t1) {
  int b = blockIdx.x, j = threadIdx.x;
  int tend = rep[b];
  if (t0 > tend) return;  // block-uniform
  int tstop = min(t1 - 1, tend);
  __shared__ __align__(16) char hq[2][HH];  // i8 h, double-buffered
  __shared__ float dlds[TT];
  int w = j >> 6, l = j & 63, lr = l & 15, lg = l >> 4;
  int u = w * 16 + lr;

  // B-fragments: wbq[g][m] = WhQ[col=g*128+u][k = m*64 + lg*16 .. +16] (16 i8)
  int4v wbq[7][2];
#pragma unroll
  for (int g = 0; g < 7; ++g)
#pragma unroll
    for (int m = 0; m < 2; ++m)
      wbq[g][m] = *(const int4v*)(WhQ + (size_t)(g * HH + u) * DD + m * 64 + lg * 16);
  float sg[7];
#pragma unroll
  for (int g = 0; g < 7; ++g) sg[g] = wscale[g * HH + u] * (1.f / 127.f);
  for (int i = j; i < TT; i += 512) dlds[i] = dur[b * TT + i];
  float c_s = 0.f, cb_s = 0.f;
  if (lg == 0) {
    hq[0][u] = (t0 == 0) ? (char)0 : st_h[b * HH + u];
    hq[1][u] = (char)0;
  }
  if (t0 != 0) {
    c_s = st_c[b * HH + u];
    cb_s = st_cb[b * HH + u];
  }
  __syncthreads();

  const _Float16* xgp = xg + (size_t)b * NGP + u * 8;  // + step*stp, aligned 16B
  const size_t stp = (size_t)BB * NGP;
  half8 cur[8], nxt[8];
#pragma unroll
  for (int i = 0; i < 8; ++i)
    cur[i] = *(const half8*)(xgp + (size_t)(min(t0 + i, tstop) - t0) * stp);
  char hqsave = 0;

#define STEP(T, CUR, PIN, POUT)                                                  \
  do {                                                                           \
    float dt = dlds[T];                                                          \
    int4v aq0 = *(const int4v*)&hq[PIN][lg * 16];                                \
    int4v aq1 = *(const int4v*)&hq[PIN][64 + lg * 16];                           \
    int4v acc[7];                                                                \
    _Pragma("unroll") for (int g = 0; g < 7; ++g) acc[g] = (int4v){0, 0, 0, 0};  \
    _Pragma("unroll") for (int g = 0; g < 7; ++g)                                \
        acc[g] = __builtin_amdgcn_mfma_i32_16x16x64_i8(aq0, wbq[g][0], acc[g], 0, 0, 0); \
    _Pragma("unroll") for (int g = 0; g < 7; ++g)                                \
        acc[g] = __builtin_amdgcn_mfma_i32_16x16x64_i8(aq1, wbq[g][1], acc[g], 0, 0, 0); \
    float gv[7];                                                                 \
    _Pragma("unroll") for (int g = 0; g < 7; ++g)                                \
        gv[g] = (float)acc[g][0] * sg[g] + (float)CUR[g];                        \
    float iv = sigmoidf_(gv[0]), fv = sigmoidf_(gv[1]);                          \
    float zv = tanhf_(gv[2]), ov = sigmoidf_(gv[3]);                             \
    float ibv = sigmoidf_(gv[4]), fbv = sigmoidf_(gv[5]);                        \
    float dv = softplusf_(gv[6]);                                                \
    float cc = fv * c_s + iv * zv;                                               \
    cb_s = fbv * cb_s + ibv * zv;                                                \
    float cn = cb_s + (cc - cb_s) * __expf(-dv * dt);                            \
    float hn = ov * tanhf_(cn);                                                  \
    c_s = cn;                                                                    \
    char hb = (char)__float2int_rn(hn * 127.f);                                  \
    hqsave = hb;                                                                 \
    if (lg == 0) {                                                               \
      if ((T) == tend) {                                                         \
        out[b * HH + u] = hn;                                                    \
        out[BB * HH + b * HH + u] = cn;                                          \
      }                                                                          \
      hq[POUT][u] = hb;                                                          \
    }                                                                            \
    __syncthreads();                                                             \
  } while (0)

  for (int tb = t0; tb <= tstop; tb += 8) {
    // issue next batch's 8 loads up front (one vmcnt-drain per 8 steps)
#pragma unroll
    for (int i = 0; i < 8; ++i)
      nxt[i] = *(const half8*)(xgp + (size_t)(min(tb + 8 + i, tstop) - t0) * stp);
    STEP(tb, cur[0], 0, 1);
    if (tb + 1 <= tstop) STEP(tb + 1, cur[1], 1, 0);
    if (tb + 2 <= tstop) STEP(tb + 2, cur[2], 0, 1);
    if (tb + 3 <= tstop) STEP(tb + 3, cur[3], 1, 0);
    if (tb + 4 <= tstop) STEP(tb + 4, cur[4], 0, 1);
    if (tb + 5 <= tstop) STEP(tb + 5, cur[5], 1, 0);
    if (tb + 6 <= tstop) STEP(tb + 6, cur[6], 0, 1);
    if (tb + 7 <= tstop) STEP(tb + 7, cur[7], 1, 0);
#pragma unroll
    for (int i = 0; i < 8; ++i) cur[i] = nxt[i];
  }
#undef STEP

  if (tstop < tend && lg == 0) {  // save state for next chunk
    st_h[b * HH + u] = hqsave;
    st_c[b * HH + u] = c_s;
    st_cb[b * HH + u] = cb_s;
  }
}

extern "C" void kernel_launch(void* const* d_in, const int* in_sizes, int n_in,
                              void* d_out, int out_size, void* d_ws, size_t ws_size,
                              hipStream_t stream) {
  const float* x = (const float*)d_in[0];
  const float* dur = (const float*)d_in[1];
  const int* rep = (const int*)d_in[2];
  const float* Wx = (const float*)d_in[3];
  const float* Wh = (const float*)d_in[4];
  const float* bias = (const float*)d_in[5];
  float* out = (float*)d_out;
  char* ws = (char*)d_ws;

  size_t off = 0;
  _Float16* WxTp = (_Float16*)(ws + off); off += (size_t)NGP * DD * 2;
  float* bias_p = (float*)(ws + off); off += (size_t)NGP * 4;
  char* WhQ = (char*)(ws + off); off += (size_t)NG * DD;
  float* wscale = (float*)(ws + off); off += (size_t)NG * 4;
  char* st_h = (char*)(ws + off); off += (size_t)BB * HH;
  float* st_c = (float*)(ws + off); off += (size_t)BB * HH * 4;
  float* st_cb = (float*)(ws + off); off += (size_t)BB * HH * 4;
  off = (off + 255) & ~(size_t)255;
  _Float16* xgbuf = (_Float16*)(ws + off);

  size_t avail = ws_size > off ? ws_size - off : 0;
  size_t perT = (size_t)BB * NGP * 2;
  int Tc = (int)(avail / perT);
  if (Tc > TT) Tc = TT;
  if (Tc < 1) Tc = 1;

  int nprep = NGP * DD + NGP;
  hipLaunchKernelGGL(wtrans_k, dim3((nprep + 255) / 256), dim3(256), 0, stream,
                     Wx, bias, WxTp, bias_p);
  hipLaunchKernelGGL(wquant_k, dim3(NG / 64), dim3(256), 0, stream,
                     Wh, WhQ, wscale);
  for (int t0 = 0; t0 < TT; t0 += Tc) {
    int t1 = t0 + Tc;
    if (t1 > TT) t1 = TT;
    int mtiles = (t1 - t0) * BB / 128;
    hipLaunchKernelGGL(xg_gemm_k, dim3(mtiles), dim3(256), 0, stream,
                       x, WxTp, bias_p, xgbuf, t0);
    hipLaunchKernelGGL(rec_k, dim3(BB), dim3(512), 0, stream,
                       xgbuf, dur, rep, WhQ, wscale, out, st_h, st_c, st_cb, t0, t1);
  }
}